// Round 8
// baseline (199.244 us; speedup 1.0000x reference)
//
#include <hip/hip_runtime.h>

#define D_MODEL 1024
#define HEADS   16
#define DK      64
#define BATCH   2
#define TSEQ    2048
#define NTOK    (BATCH * TSEQ)   // 4096

typedef __attribute__((ext_vector_type(8))) short bf16x8;
typedef __attribute__((ext_vector_type(4))) short s16x4;
typedef __attribute__((ext_vector_type(4))) float f32x4;

__device__ __forceinline__ short f2bf(float f) {
    union { float f; unsigned u; } a;
    a.f = f;
    unsigned r = a.u + 0x7FFFu + ((a.u >> 16) & 1u);
    return (short)(r >> 16);
}
// pack two non-negative floats to bf16x2 (round-to-nearest, ties away)
__device__ __forceinline__ unsigned pk_bf16_rn(float a, float b) {
    union { float f; unsigned u; } x, y;
    x.f = a; y.f = b;
    return __builtin_amdgcn_perm(y.u + 0x8000u, x.u + 0x8000u, 0x07060302u);
}

// async global->LDS, 16B per lane. LDS dest = wave-uniform base + lane*16.
__device__ __forceinline__ void gl_lds16(const void* g, void* l) {
    __builtin_amdgcn_global_load_lds(
        (const __attribute__((address_space(1))) unsigned int*)(unsigned long long)g,
        (__attribute__((address_space(3))) unsigned int*)(unsigned int)(unsigned long long)l,
        16, 0, 0);
}

// ------------------------------------------------- fused prep: transposes + cvt
__global__ __launch_bounds__(256) void prep_kernel(
    const float* __restrict__ x, const float* __restrict__ Wqkv,
    const float* __restrict__ Wout,
    short* __restrict__ xb, short* __restrict__ wqkvt, short* __restrict__ woutt)
{
    int bx = blockIdx.x;
    if (bx < 4096) {
        __shared__ float tile[32][33];
        const float* in; short* out; int N, n0, k0;
        if (bx < 3072) { in = Wqkv; out = wqkvt; N = 3072; n0 = (bx % 96) * 32; k0 = (bx / 96) * 32; }
        else { int t2 = bx - 3072; in = Wout; out = woutt; N = 1024; n0 = (t2 & 31) * 32; k0 = (t2 >> 5) * 32; }
        int tx = threadIdx.x & 31, ty = threadIdx.x >> 5;
        #pragma unroll
        for (int i = 0; i < 32; i += 8)
            tile[ty + i][tx] = in[(long)(k0 + ty + i) * N + n0 + tx];
        __syncthreads();
        #pragma unroll
        for (int i = 0; i < 32; i += 8)
            out[(long)(n0 + ty + i) * 1024 + k0 + tx] = f2bf(tile[tx][ty + i]);
    } else {
        long i = ((long)(bx - 4096) * 256 + threadIdx.x) * 4;
        float4 v = *(const float4*)&x[i];
        s16x4 o;
        o[0] = f2bf(v.x); o[1] = f2bf(v.y); o[2] = f2bf(v.z); o[3] = f2bf(v.w);
        *(s16x4*)&xb[i] = o;
    }
}

// ---------------------------------------------------------------- bf16 MFMA GEMM
template<int MODE>
__global__ __launch_bounds__(256) void gemm_bf16_kernel(
    const short* __restrict__ A, const short* __restrict__ Bt,
    const float* __restrict__ bias,
    short* __restrict__ qo, short* __restrict__ ko, short* __restrict__ vt,
    float* __restrict__ fout)
{
    const int K = 1024;
    __shared__ short As[128 * 64];   // [row*64 + (chunk^(row&7))*8]
    __shared__ short Bs[128 * 64];

    int tid  = threadIdx.x;
    int wid  = tid >> 6, lane = tid & 63;
    int wm   = wid >> 1, wn   = wid & 1;
    int g    = lane >> 4, l15 = lane & 15;
    int swzr = l15 & 7;
    long m0  = (long)blockIdx.x * 128;
    long n0  = (long)blockIdx.y * 128;

    f32x4 acc[4][4];
    #pragma unroll
    for (int i = 0; i < 4; i++)
        #pragma unroll
        for (int j = 0; j < 4; j++)
            acc[i][j] = (f32x4){0.f, 0.f, 0.f, 0.f};

    int srow = wid * 32 + (lane >> 3);
    int sch  = ((lane & 7) ^ ((lane >> 3) & 7)) * 8;   // shorts
    const short* Abase = A  + (m0 + srow) * K + sch;
    const short* Bbase = Bt + (n0 + srow) * K + sch;
    short* adst = &As[wid * 32 * 64];
    short* bdst = &Bs[wid * 32 * 64];

    for (int k0 = 0; k0 < K; k0 += 64) {
        #pragma unroll
        for (int s = 0; s < 4; s++) {
            gl_lds16(Abase + (long)s * 8 * K + k0, adst + s * 8 * 64);
            gl_lds16(Bbase + (long)s * 8 * K + k0, bdst + s * 8 * 64);
        }
        __syncthreads();

        bf16x8 af[4][2], bfr[4][2];
        #pragma unroll
        for (int i = 0; i < 4; i++)
            #pragma unroll
            for (int c = 0; c < 2; c++)
                af[i][c] = *(const bf16x8*)&As[(wm * 64 + i * 16 + l15) * 64 + (((c * 4 + g) ^ swzr) << 3)];
        #pragma unroll
        for (int j = 0; j < 4; j++)
            #pragma unroll
            for (int c = 0; c < 2; c++)
                bfr[j][c] = *(const bf16x8*)&Bs[(wn * 64 + j * 16 + l15) * 64 + (((c * 4 + g) ^ swzr) << 3)];

        #pragma unroll
        for (int c = 0; c < 2; c++)
            #pragma unroll
            for (int i = 0; i < 4; i++)
                #pragma unroll
                for (int j = 0; j < 4; j++)
                    acc[i][j] = __builtin_amdgcn_mfma_f32_16x16x32_bf16(af[i][c], bfr[j][c], acc[i][j], 0, 0, 0);

        __syncthreads();
    }

    // epilogue: D[m = (lane>>4)*4 + reg][n = lane&15]
    #pragma unroll
    for (int j = 0; j < 4; j++) {
        int n = (int)n0 + wn * 64 + j * 16 + l15;
        float bb = bias[n];
        #pragma unroll
        for (int i = 0; i < 4; i++) {
            int mrow = (int)m0 + wm * 64 + i * 16 + g * 4;
            if (MODE == 1) {
                #pragma unroll
                for (int r = 0; r < 4; r++)
                    fout[(long)(mrow + r) * 1024 + n] = acc[i][j][r] + bb;
            } else {
                if (n < 1024) {
                    const float QS = 0.125f * 1.44269504088896f;   // log2e/sqrt(dk)
                    #pragma unroll
                    for (int r = 0; r < 4; r++)
                        qo[(long)(mrow + r) * 1024 + n] = f2bf((acc[i][j][r] + bb) * QS);
                } else if (n < 2048) {
                    #pragma unroll
                    for (int r = 0; r < 4; r++)
                        ko[(long)(mrow + r) * 1024 + (n - 1024)] = f2bf(acc[i][j][r] + bb);
                } else {
                    int c = n - 2048, h = c >> 6, d = c & 63;
                    int b = mrow >> 11, t = mrow & 2047;
                    s16x4 pk;
                    #pragma unroll
                    for (int r = 0; r < 4; r++) pk[r] = f2bf(acc[i][j][r] + bb);
                    *(s16x4*)&vt[((long)((b * 16 + h) * 64 + d)) * 2048 + t] = pk;
                }
            }
        }
    }
}

// ---------------------------------------------------------------- flash, split-K x2
// grid (TSEQ/128, 2*BH). 32-key K tiles (rows 128 B, XOR-swizzled) + V packed
// 2 d-rows per 128 B LDS row (XOR-swizzled via per-lane SOURCE permute, since
// the DMA fixes lane->slot). Wave w stages 512 shorts at base wid*512 (R7 bug:
// was wid*1024 -> OOB into plds -> NaN).
__global__ __launch_bounds__(256) void flash_split_kernel(
    const short* __restrict__ qb, const short* __restrict__ kb,
    const short* __restrict__ vt, float* __restrict__ Opart,
    float* __restrict__ lpart)
{
    __shared__ short Ks[2][32 * 64];   // [buf][key*64 + (chunk^(key&7))*8]
    __shared__ short Vs[2][32 * 64];   // [buf][R*64 + p*8], slot (R,p) holds
                                       //   d=2R+((p^(R&7))>>2), keychunk=(p^(R&7))&3
    __shared__ short plds[4][16 * 40]; // per-wave P tile, pitch 40 shorts

    int tid = threadIdx.x, wid = tid >> 6, lane = tid & 63;
    int g = lane >> 4, l15 = lane & 15;
    int swzr = l15 & 7;
    int yy = blockIdx.y, half = yy & 1, bh = yy >> 1;
    int b = bh >> 4, h = bh & 15;
    int q0w = blockIdx.x * 128 + wid * 32;
    long qrow = (long)b * TSEQ + q0w;

    bf16x8 qf[2][2];
    #pragma unroll
    for (int qg = 0; qg < 2; qg++)
        #pragma unroll
        for (int c = 0; c < 2; c++)
            qf[qg][c] = *(const bf16x8*)&qb[(qrow + qg * 16 + l15) * 1024 + h * 64 + c * 32 + g * 8];

    bf16x8 ones;
    #pragma unroll
    for (int j = 0; j < 8; j++) ones[j] = (short)0x3F80;   // bf16 1.0

    f32x4 oacc[2][4], lacc[2];
    #pragma unroll
    for (int qg = 0; qg < 2; qg++) {
        lacc[qg] = (f32x4){0.f, 0.f, 0.f, 0.f};
        #pragma unroll
        for (int jt = 0; jt < 4; jt++) oacc[qg][jt] = (f32x4){0.f, 0.f, 0.f, 0.f};
    }

    // this block's key range: [half*1024, half*1024 + 1024), in 32-key tiles
    const short* kg = kb + ((long)b * TSEQ + half * 1024) * 1024 + h * 64;  // +key*1024+d
    const short* vg = vt + ((long)bh * 64) * 2048 + half * 1024;            // +d*2048+key

    // K staging: lane i -> slot row kr = wid*8+(i>>3), pos i&7, source chunk (i&7)^(kr&7)
    int kr  = wid * 8 + (lane >> 3);
    int kch = ((lane & 7) ^ ((lane >> 3) & 7)) * 8;
    // V staging (packed pairs): lane i -> slot (R = wid*8+(i>>3), p = i&7);
    // source raw chunk c = p^(R&7) -> d = 2R+(c>>2), key chunk (c&3)*8
    int Rv  = wid * 8 + (lane >> 3);
    int vc  = (lane & 7) ^ (Rv & 7);
    int vd  = 2 * Rv + (vc >> 2);
    int vch = (vc & 3) * 8;
    const short* vsrc = vg + (long)vd * 2048 + vch;

    #define STAGE(buf, kt)                                                       \
        gl_lds16(kg + (long)((kt) * 32 + kr) * 1024 + kch, &Ks[buf][wid * 512]); \
        gl_lds16(vsrc + (kt) * 32,                         &Vs[buf][wid * 512]);

    #define BODY(cur, nxt, kt, do_pref)                                              \
    {                                                                                \
        if (do_pref) { STAGE(nxt, (kt) + 1) }                                        \
        bf16x8 kf[2][2], vf[4];                                                      \
        _Pragma("unroll")                                                            \
        for (int jt = 0; jt < 2; jt++)                                               \
            _Pragma("unroll")                                                        \
            for (int c = 0; c < 2; c++)                                              \
                kf[jt][c] = *(const bf16x8*)&Ks[cur][(jt * 16 + l15) * 64 + (((c * 4 + g) ^ swzr) << 3)]; \
        _Pragma("unroll")                                                            \
        for (int jt = 0; jt < 4; jt++) {                                             \
            int vrow = l15 >> 1;                                                     \
            vf[jt] = *(const bf16x8*)&Vs[cur][(jt * 8 + vrow) * 64 + (((((l15 & 1) * 4 + g)) ^ vrow) << 3)]; \
        }                                                                            \
        _Pragma("unroll")                                                            \
        for (int qg = 0; qg < 2; qg++) {                                             \
            f32x4 s[2];                                                              \
            _Pragma("unroll")                                                        \
            for (int jt = 0; jt < 2; jt++) {                                         \
                f32x4 t = (f32x4){0.f, 0.f, 0.f, 0.f};                               \
                t = __builtin_amdgcn_mfma_f32_16x16x32_bf16(kf[jt][0], qf[qg][0], t, 0, 0, 0); \
                t = __builtin_amdgcn_mfma_f32_16x16x32_bf16(kf[jt][1], qf[qg][1], t, 0, 0, 0); \
                s[jt] = t;                                                           \
            }                                                                        \
            _Pragma("unroll")                                                        \
            for (int jt = 0; jt < 2; jt++) {                                         \
                float p0 = __builtin_amdgcn_exp2f(s[jt][0]);                         \
                float p1 = __builtin_amdgcn_exp2f(s[jt][1]);                         \
                float p2 = __builtin_amdgcn_exp2f(s[jt][2]);                         \
                float p3 = __builtin_amdgcn_exp2f(s[jt][3]);                         \
                uint2 pk;                                                            \
                pk.x = pk_bf16_rn(p0, p1);                                           \
                pk.y = pk_bf16_rn(p2, p3);                                           \
                *(uint2*)&plds[wid][l15 * 40 + jt * 16 + g * 4] = pk;                \
            }                                                                        \
            bf16x8 pA = *(const bf16x8*)&plds[wid][l15 * 40 + g * 8];                \
            lacc[qg] = __builtin_amdgcn_mfma_f32_16x16x32_bf16(pA, ones, lacc[qg], 0, 0, 0); \
            _Pragma("unroll")                                                        \
            for (int jt = 0; jt < 4; jt++)                                           \
                oacc[qg][jt] = __builtin_amdgcn_mfma_f32_16x16x32_bf16(pA, vf[jt], oacc[qg][jt], 0, 0, 0); \
        }                                                                            \
        __syncthreads();                                                             \
    }

    STAGE(0, 0)
    __syncthreads();

    for (int kt = 0; kt < 32; kt += 2) {
        BODY(0, 1, kt, 1)
        BODY(1, 0, kt + 1, (kt + 2 < 32))
    }
    #undef BODY
    #undef STAGE

    // write unnormalized partials (fp32). lacc cols identical; l15==0 lanes carry l.
    #pragma unroll
    for (int qg = 0; qg < 2; qg++) {
        #pragma unroll
        for (int r = 0; r < 4; r++) {
            long tok = qrow + qg * 16 + g * 4 + r;
            #pragma unroll
            for (int jt = 0; jt < 4; jt++)
                Opart[((long)half * NTOK + tok) * 1024 + h * 64 + jt * 16 + l15] = oacc[qg][jt][r];
        }
        if (l15 == 0) {
            #pragma unroll
            for (int r = 0; r < 4; r++)
                lpart[(long)(half * 32 + bh) * 2048 + q0w + qg * 16 + g * 4 + r] = lacc[qg][r];
        }
    }
}

// ---------------------------------------------------------------- combine halves
__global__ __launch_bounds__(256) void combine_kernel(
    const float* __restrict__ Op, const float* __restrict__ lp,
    short* __restrict__ ob)
{
    long i = ((long)blockIdx.x * 256 + threadIdx.x) * 4;
    int tok = (int)(i >> 10), col = (int)(i & 1023);
    int b = tok >> 11, t = tok & 2047, h = col >> 6;
    int bh = b * 16 + h;
    float l0 = lp[(long)bh * 2048 + t];
    float l1 = lp[(long)(32 + bh) * 2048 + t];
    float inv = 1.f / (l0 + l1);
    float4 o0 = *(const float4*)&Op[i];
    float4 o1 = *(const float4*)&Op[(long)NTOK * 1024 + i];
    s16x4 o;
    o[0] = f2bf((o0.x + o1.x) * inv);
    o[1] = f2bf((o0.y + o1.y) * inv);
    o[2] = f2bf((o0.z + o1.z) * inv);
    o[3] = f2bf((o0.w + o1.w) * inv);
    *(s16x4*)&ob[i] = o;
}

// ---------------------------------------------------------------- fallback flash
// (R6 single-pass version, used only if ws too small for split-K partials)
__global__ __launch_bounds__(256) void flash_full_kernel(
    const short* __restrict__ qb, const short* __restrict__ kb,
    const short* __restrict__ vt, short* __restrict__ ob)
{
    __shared__ short Ks[2][64 * 64];
    __shared__ short Vs[2][64 * 64];
    __shared__ short plds[4][2][16][72];

    int tid = threadIdx.x, wid = tid >> 6, lane = tid & 63;
    int g = lane >> 4, l15 = lane & 15;
    int swzr = l15 & 7;
    int bh = blockIdx.y, b = bh >> 4, h = bh & 15;
    int q0w = blockIdx.x * 128 + wid * 32;
    long qrow = (long)b * TSEQ + q0w;

    bf16x8 qf[2][2];
    #pragma unroll
    for (int qg = 0; qg < 2; qg++)
        #pragma unroll
        for (int c = 0; c < 2; c++)
            qf[qg][c] = *(const bf16x8*)&qb[(qrow + qg * 16 + l15) * 1024 + h * 64 + c * 32 + g * 8];

    bf16x8 ones;
    #pragma unroll
    for (int j = 0; j < 8; j++) ones[j] = (short)0x3F80;

    f32x4 oacc[2][4], lacc[2];
    #pragma unroll
    for (int qg = 0; qg < 2; qg++) {
        lacc[qg] = (f32x4){0.f, 0.f, 0.f, 0.f};
        #pragma unroll
        for (int jt = 0; jt < 4; jt++) oacc[qg][jt] = (f32x4){0.f, 0.f, 0.f, 0.f};
    }

    const short* kg = kb + ((long)b * TSEQ) * 1024 + h * 64;
    const short* vg = vt + ((long)bh * 64) * 2048;

    int ch = (((lane & 7) ^ ((lane >> 3) & 7))) * 8;
    int r0 = wid * 16 + (lane >> 3);
    int r1 = r0 + 8;
    short* kdst0 = &Ks[0][(wid * 2 + 0) * 512];
    short* kdst1 = &Ks[0][(wid * 2 + 1) * 512];
    short* vdst0 = &Vs[0][(wid * 2 + 0) * 512];
    short* vdst1 = &Vs[0][(wid * 2 + 1) * 512];

    #define STAGE(buf, kt)                                                        \
        gl_lds16(kg + (long)((kt) * 64 + r0) * 1024 + ch, kdst0 + (buf) * 4096);  \
        gl_lds16(kg + (long)((kt) * 64 + r1) * 1024 + ch, kdst1 + (buf) * 4096);  \
        gl_lds16(vg + (long)r0 * 2048 + (kt) * 64 + ch,   vdst0 + (buf) * 4096);  \
        gl_lds16(vg + (long)r1 * 2048 + (kt) * 64 + ch,   vdst1 + (buf) * 4096);

    #define BODY(cur, nxt, kt, do_pref)                                                  \
    {                                                                                    \
        if (do_pref) { STAGE(nxt, (kt) + 1) }                                            \
        bf16x8 kf[4][2], vf[4][2];                                                       \
        _Pragma("unroll")                                                                \
        for (int jt = 0; jt < 4; jt++)                                                   \
            _Pragma("unroll")                                                            \
            for (int c = 0; c < 2; c++) {                                                \
                int off = (jt * 16 + l15) * 64 + (((c * 4 + g) ^ swzr) << 3);            \
                kf[jt][c] = *(const bf16x8*)&Ks[cur][off];                               \
                vf[jt][c] = *(const bf16x8*)&Vs[cur][off];                               \
            }                                                                            \
        _Pragma("unroll")                                                                \
        for (int qg = 0; qg < 2; qg++) {                                                 \
            f32x4 s[4];                                                                  \
            _Pragma("unroll")                                                            \
            for (int jt = 0; jt < 4; jt++) {                                             \
                f32x4 t = (f32x4){0.f, 0.f, 0.f, 0.f};                                   \
                t = __builtin_amdgcn_mfma_f32_16x16x32_bf16(kf[jt][0], qf[qg][0], t, 0, 0, 0); \
                t = __builtin_amdgcn_mfma_f32_16x16x32_bf16(kf[jt][1], qf[qg][1], t, 0, 0, 0); \
                s[jt] = t;                                                               \
            }                                                                            \
            _Pragma("unroll")                                                            \
            for (int jt = 0; jt < 4; jt++) {                                             \
                float p0 = __builtin_amdgcn_exp2f(s[jt][0]);                             \
                float p1 = __builtin_amdgcn_exp2f(s[jt][1]);                             \
                float p2 = __builtin_amdgcn_exp2f(s[jt][2]);                             \
                float p3 = __builtin_amdgcn_exp2f(s[jt][3]);                             \
                uint2 pk;                                                                \
                pk.x = pk_bf16_rn(p0, p1);                                               \
                pk.y = pk_bf16_rn(p2, p3);                                               \
                *(uint2*)&plds[wid][qg][l15][jt * 16 + g * 4] = pk;                      \
            }                                                                            \
            bf16x8 pA0 = *(const bf16x8*)&plds[wid][qg][l15][g * 8];                     \
            bf16x8 pA1 = *(const bf16x8*)&plds[wid][qg][l15][32 + g * 8];                \
            lacc[qg] = __builtin_amdgcn_mfma_f32_16x16x32_bf16(pA0, ones, lacc[qg], 0, 0, 0); \
            lacc[qg] = __builtin_amdgcn_mfma_f32_16x16x32_bf16(pA1, ones, lacc[qg], 0, 0, 0); \
            _Pragma("unroll")                                                            \
            for (int jt = 0; jt < 4; jt++) {                                             \
                oacc[qg][jt] = __builtin_amdgcn_mfma_f32_16x16x32_bf16(pA0, vf[jt][0], oacc[qg][jt], 0, 0, 0); \
                oacc[qg][jt] = __builtin_amdgcn_mfma_f32_16x16x32_bf16(pA1, vf[jt][1], oacc[qg][jt], 0, 0, 0); \
            }                                                                            \
        }                                                                                \
        __syncthreads();                                                                 \
    }

    STAGE(0, 0)
    __syncthreads();

    for (int kt = 0; kt < TSEQ / 64; kt += 2) {
        BODY(0, 1, kt, 1)
        BODY(1, 0, kt + 1, (kt + 2 < TSEQ / 64))
    }
    #undef BODY
    #undef STAGE

    #pragma unroll
    for (int qg = 0; qg < 2; qg++)
        #pragma unroll
        for (int r = 0; r < 4; r++) {
            float inv = 1.f / lacc[qg][r];
            long row = qrow + qg * 16 + g * 4 + r;
            #pragma unroll
            for (int jt = 0; jt < 4; jt++)
                ob[row * 1024 + h * 64 + jt * 16 + l15] = f2bf(oacc[qg][jt][r] * inv);
        }
}

// ---------------------------------------------------------------- launcher
extern "C" void kernel_launch(void* const* d_in, const int* in_sizes, int n_in,
                              void* d_out, int out_size, void* d_ws, size_t ws_size,
                              hipStream_t stream)
{
    const float* x    = (const float*)d_in[0];
    const float* Wqkv = (const float*)d_in[1];
    const float* bqkv = (const float*)d_in[2];
    const float* Wout = (const float*)d_in[3];
    const float* bout = (const float*)d_in[4];
    float* out = (float*)d_out;

    char* ws = (char*)d_ws;
    const size_t SZ_TOKD = (size_t)NTOK * 1024 * sizeof(short);   // 8 MB
    short* xb    = (short*)ws;                 ws += SZ_TOKD;
    short* wqkvt = (short*)ws;                 ws += (size_t)3072 * 1024 * sizeof(short);
    short* woutt = (short*)ws;                 ws += (size_t)1024 * 1024 * sizeof(short);
    short* qb    = (short*)ws;                 ws += SZ_TOKD;
    short* kb    = (short*)ws;                 ws += SZ_TOKD;
    short* vt    = (short*)ws;                 ws += SZ_TOKD;
    short* ob    = (short*)ws;                 ws += SZ_TOKD;
    size_t base_need = (size_t)(ws - (char*)d_ws);
    float* Opart = (float*)ws;                 ws += (size_t)2 * NTOK * 1024 * sizeof(float);
    float* lpart = (float*)ws;                 ws += (size_t)2 * 32 * 2048 * sizeof(float);
    size_t split_need = (size_t)(ws - (char*)d_ws);
    if (base_need > ws_size) return;
    bool use_split = (split_need <= ws_size);

    prep_kernel<<<8192, 256, 0, stream>>>(x, Wqkv, Wout, xb, wqkvt, woutt);

    gemm_bf16_kernel<0><<<dim3(NTOK / 128, 3072 / 128), 256, 0, stream>>>(
        xb, wqkvt, bqkv, qb, kb, vt, nullptr);

    if (use_split) {
        flash_split_kernel<<<dim3(TSEQ / 128, 2 * BATCH * HEADS), 256, 0, stream>>>(
            qb, kb, vt, Opart, lpart);
        combine_kernel<<<NTOK * 1024 / 4 / 256, 256, 0, stream>>>(Opart, lpart, ob);
    } else {
        flash_full_kernel<<<dim3(TSEQ / 128, BATCH * HEADS), 256, 0, stream>>>(qb, kb, vt, ob);
    }

    gemm_bf16_kernel<1><<<dim3(NTOK / 128, 1024 / 128), 256, 0, stream>>>(
        ob, woutt, bout, nullptr, nullptr, nullptr, out);
}

// Round 9
// 188.987 us; speedup vs baseline: 1.0543x; 1.0543x over previous
//
#include <hip/hip_runtime.h>

#define D_MODEL 1024
#define HEADS   16
#define DK      64
#define BATCH   2
#define TSEQ    2048
#define NTOK    (BATCH * TSEQ)   // 4096

typedef __attribute__((ext_vector_type(8))) short bf16x8;
typedef __attribute__((ext_vector_type(4))) short s16x4;
typedef __attribute__((ext_vector_type(4))) float f32x4;

__device__ __forceinline__ short f2bf(float f) {
    union { float f; unsigned u; } a;
    a.f = f;
    unsigned r = a.u + 0x7FFFu + ((a.u >> 16) & 1u);
    return (short)(r >> 16);
}
// pack two non-negative floats to bf16x2 (round-to-nearest, ties away)
__device__ __forceinline__ unsigned pk_bf16_rn(float a, float b) {
    union { float f; unsigned u; } x, y;
    x.f = a; y.f = b;
    return __builtin_amdgcn_perm(y.u + 0x8000u, x.u + 0x8000u, 0x07060302u);
}

// async global->LDS, 16B per lane. LDS dest = wave-uniform base + lane*16.
__device__ __forceinline__ void gl_lds16(const void* g, void* l) {
    __builtin_amdgcn_global_load_lds(
        (const __attribute__((address_space(1))) unsigned int*)(unsigned long long)g,
        (__attribute__((address_space(3))) unsigned int*)(unsigned int)(unsigned long long)l,
        16, 0, 0);
}

// ------------------------------------------------- fused prep: transposes + cvt
// blocks [0,3072): Wqkv [1024][3072] -> wqkvt [3072][1024] bf16
// blocks [3072,4096): Wout [1024][1024] -> woutt [1024][1024] bf16
// blocks [4096,8192): x fp32 -> xb bf16 (4 elems/thread)
__global__ __launch_bounds__(256) void prep_kernel(
    const float* __restrict__ x, const float* __restrict__ Wqkv,
    const float* __restrict__ Wout,
    short* __restrict__ xb, short* __restrict__ wqkvt, short* __restrict__ woutt)
{
    int bx = blockIdx.x;
    if (bx < 4096) {
        __shared__ float tile[32][33];
        const float* in; short* out; int N, n0, k0;
        if (bx < 3072) { in = Wqkv; out = wqkvt; N = 3072; n0 = (bx % 96) * 32; k0 = (bx / 96) * 32; }
        else { int t2 = bx - 3072; in = Wout; out = woutt; N = 1024; n0 = (t2 & 31) * 32; k0 = (t2 >> 5) * 32; }
        int tx = threadIdx.x & 31, ty = threadIdx.x >> 5;
        #pragma unroll
        for (int i = 0; i < 32; i += 8)
            tile[ty + i][tx] = in[(long)(k0 + ty + i) * N + n0 + tx];
        __syncthreads();
        #pragma unroll
        for (int i = 0; i < 32; i += 8)
            out[(long)(n0 + ty + i) * 1024 + k0 + tx] = f2bf(tile[tx][ty + i]);
    } else {
        long i = ((long)(bx - 4096) * 256 + threadIdx.x) * 4;
        float4 v = *(const float4*)&x[i];
        s16x4 o;
        o[0] = f2bf(v.x); o[1] = f2bf(v.y); o[2] = f2bf(v.z); o[3] = f2bf(v.w);
        *(s16x4*)&xb[i] = o;
    }
}

// ---------------------------------------------------------------- bf16 MFMA GEMM
// m97-style: global_load_lds width-16 staging, 128x64 LDS tiles, XOR chunk
// swizzle (conflict-free staging + ds_read_b128), 32 MFMA per barrier-pair.
// MODE 0: QKV epilogue -> q (pre-scaled by log2e/8), k, vt[(b*16+h)*64+d][2048]
// MODE 1: out-proj     -> fp32 out[tok][1024]
template<int MODE>
__global__ __launch_bounds__(256) void gemm_bf16_kernel(
    const short* __restrict__ A, const short* __restrict__ Bt,
    const float* __restrict__ bias,
    short* __restrict__ qo, short* __restrict__ ko, short* __restrict__ vt,
    float* __restrict__ fout)
{
    const int K = 1024;
    __shared__ short As[128 * 64];   // [row*64 + (chunk^(row&7))*8]
    __shared__ short Bs[128 * 64];

    int tid  = threadIdx.x;
    int wid  = tid >> 6, lane = tid & 63;
    int wm   = wid >> 1, wn   = wid & 1;
    int g    = lane >> 4, l15 = lane & 15;
    int swzr = l15 & 7;
    long m0  = (long)blockIdx.x * 128;
    long n0  = (long)blockIdx.y * 128;

    f32x4 acc[4][4];
    #pragma unroll
    for (int i = 0; i < 4; i++)
        #pragma unroll
        for (int j = 0; j < 4; j++)
            acc[i][j] = (f32x4){0.f, 0.f, 0.f, 0.f};

    int srow = wid * 32 + (lane >> 3);
    int sch  = ((lane & 7) ^ ((lane >> 3) & 7)) * 8;   // shorts
    const short* Abase = A  + (m0 + srow) * K + sch;
    const short* Bbase = Bt + (n0 + srow) * K + sch;
    short* adst = &As[wid * 32 * 64];
    short* bdst = &Bs[wid * 32 * 64];

    for (int k0 = 0; k0 < K; k0 += 64) {
        #pragma unroll
        for (int s = 0; s < 4; s++) {
            gl_lds16(Abase + (long)s * 8 * K + k0, adst + s * 8 * 64);
            gl_lds16(Bbase + (long)s * 8 * K + k0, bdst + s * 8 * 64);
        }
        __syncthreads();

        bf16x8 af[4][2], bfr[4][2];
        #pragma unroll
        for (int i = 0; i < 4; i++)
            #pragma unroll
            for (int c = 0; c < 2; c++)
                af[i][c] = *(const bf16x8*)&As[(wm * 64 + i * 16 + l15) * 64 + (((c * 4 + g) ^ swzr) << 3)];
        #pragma unroll
        for (int j = 0; j < 4; j++)
            #pragma unroll
            for (int c = 0; c < 2; c++)
                bfr[j][c] = *(const bf16x8*)&Bs[(wn * 64 + j * 16 + l15) * 64 + (((c * 4 + g) ^ swzr) << 3)];

        #pragma unroll
        for (int c = 0; c < 2; c++)
            #pragma unroll
            for (int i = 0; i < 4; i++)
                #pragma unroll
                for (int j = 0; j < 4; j++)
                    acc[i][j] = __builtin_amdgcn_mfma_f32_16x16x32_bf16(af[i][c], bfr[j][c], acc[i][j], 0, 0, 0);

        __syncthreads();
    }

    // epilogue: D[m = (lane>>4)*4 + reg][n = lane&15]
    #pragma unroll
    for (int j = 0; j < 4; j++) {
        int n = (int)n0 + wn * 64 + j * 16 + l15;
        float bb = bias[n];
        #pragma unroll
        for (int i = 0; i < 4; i++) {
            int mrow = (int)m0 + wm * 64 + i * 16 + g * 4;
            if (MODE == 1) {
                #pragma unroll
                for (int r = 0; r < 4; r++)
                    fout[(long)(mrow + r) * 1024 + n] = acc[i][j][r] + bb;
            } else {
                if (n < 1024) {
                    const float QS = 0.125f * 1.44269504088896f;   // log2e/sqrt(dk)
                    #pragma unroll
                    for (int r = 0; r < 4; r++)
                        qo[(long)(mrow + r) * 1024 + n] = f2bf((acc[i][j][r] + bb) * QS);
                } else if (n < 2048) {
                    #pragma unroll
                    for (int r = 0; r < 4; r++)
                        ko[(long)(mrow + r) * 1024 + (n - 1024)] = f2bf(acc[i][j][r] + bb);
                } else {
                    int c = n - 2048, h = c >> 6, d = c & 63;
                    int b = mrow >> 11, t = mrow & 2047;
                    s16x4 pk;
                    #pragma unroll
                    for (int r = 0; r < 4; r++) pk[r] = f2bf(acc[i][j][r] + bb);
                    *(s16x4*)&vt[((long)((b * 16 + h) * 64 + d)) * 2048 + t] = pk;
                }
            }
        }
    }
}

// ---------------------------------------------------------------- flash attention
// grid: (TSEQ/128, BATCH*HEADS), block 256 = 4 waves x 32 queries (R6 version —
// R8's split-K x2 proved flash is LDS-throughput-bound, not latency-bound:
// 2x occupancy gave 0% speedup and the combine kernel cost 8 µs + 33 MB).
__global__ __launch_bounds__(256) void flash_attn_kernel(
    const short* __restrict__ qb, const short* __restrict__ kb,
    const short* __restrict__ vt, short* __restrict__ ob)
{
    __shared__ short Ks[2][64 * 64];          // [buf][key*64 + swz(chunk)*8]
    __shared__ short Vs[2][64 * 64];          // [buf][d*64 + swz(chunk)*8]
    __shared__ short plds[4][2][16][72];      // per-wave, per-qgroup P tile

    int tid = threadIdx.x, wid = tid >> 6, lane = tid & 63;
    int g = lane >> 4, l15 = lane & 15;
    int swzr = l15 & 7;
    int bh = blockIdx.y, b = bh >> 4, h = bh & 15;
    int q0w = blockIdx.x * 128 + wid * 32;
    long qrow = (long)b * TSEQ + q0w;

    bf16x8 qf[2][2];
    #pragma unroll
    for (int qg = 0; qg < 2; qg++)
        #pragma unroll
        for (int c = 0; c < 2; c++)
            qf[qg][c] = *(const bf16x8*)&qb[(qrow + qg * 16 + l15) * 1024 + h * 64 + c * 32 + g * 8];

    bf16x8 ones;
    #pragma unroll
    for (int j = 0; j < 8; j++) ones[j] = (short)0x3F80;   // bf16 1.0

    f32x4 oacc[2][4], lacc[2];
    #pragma unroll
    for (int qg = 0; qg < 2; qg++) {
        lacc[qg] = (f32x4){0.f, 0.f, 0.f, 0.f};
        #pragma unroll
        for (int jt = 0; jt < 4; jt++) oacc[qg][jt] = (f32x4){0.f, 0.f, 0.f, 0.f};
    }

    const short* kg = kb + ((long)b * TSEQ) * 1024 + h * 64;   // + key*1024 + d
    const short* vg = vt + ((long)bh * 64) * 2048;             // + d*2048 + key

    int ch = (((lane & 7) ^ ((lane >> 3) & 7))) * 8;   // swizzled global chunk offset
    int r0 = wid * 16 + (lane >> 3);
    int r1 = r0 + 8;
    short* kdst0 = &Ks[0][(wid * 2 + 0) * 512];
    short* kdst1 = &Ks[0][(wid * 2 + 1) * 512];
    short* vdst0 = &Vs[0][(wid * 2 + 0) * 512];
    short* vdst1 = &Vs[0][(wid * 2 + 1) * 512];

    #define STAGE(buf, kt)                                                        \
        gl_lds16(kg + (long)((kt) * 64 + r0) * 1024 + ch, kdst0 + (buf) * 4096);  \
        gl_lds16(kg + (long)((kt) * 64 + r1) * 1024 + ch, kdst1 + (buf) * 4096);  \
        gl_lds16(vg + (long)r0 * 2048 + (kt) * 64 + ch,   vdst0 + (buf) * 4096);  \
        gl_lds16(vg + (long)r1 * 2048 + (kt) * 64 + ch,   vdst1 + (buf) * 4096);

    #define BODY(cur, nxt, kt, do_pref)                                                  \
    {                                                                                    \
        if (do_pref) { STAGE(nxt, (kt) + 1) }                                            \
        bf16x8 kf[4][2], vf[4][2];                                                       \
        _Pragma("unroll")                                                                \
        for (int jt = 0; jt < 4; jt++)                                                   \
            _Pragma("unroll")                                                            \
            for (int c = 0; c < 2; c++) {                                                \
                int off = (jt * 16 + l15) * 64 + (((c * 4 + g) ^ swzr) << 3);            \
                kf[jt][c] = *(const bf16x8*)&Ks[cur][off];                               \
                vf[jt][c] = *(const bf16x8*)&Vs[cur][off];                               \
            }                                                                            \
        _Pragma("unroll")                                                                \
        for (int qg = 0; qg < 2; qg++) {                                                 \
            f32x4 s[4];                                                                  \
            _Pragma("unroll")                                                            \
            for (int jt = 0; jt < 4; jt++) {                                             \
                f32x4 t = (f32x4){0.f, 0.f, 0.f, 0.f};                                   \
                t = __builtin_amdgcn_mfma_f32_16x16x32_bf16(kf[jt][0], qf[qg][0], t, 0, 0, 0); \
                t = __builtin_amdgcn_mfma_f32_16x16x32_bf16(kf[jt][1], qf[qg][1], t, 0, 0, 0); \
                s[jt] = t;                                                               \
            }                                                                            \
            _Pragma("unroll")                                                            \
            for (int jt = 0; jt < 4; jt++) {                                             \
                float p0 = __builtin_amdgcn_exp2f(s[jt][0]);                             \
                float p1 = __builtin_amdgcn_exp2f(s[jt][1]);                             \
                float p2 = __builtin_amdgcn_exp2f(s[jt][2]);                             \
                float p3 = __builtin_amdgcn_exp2f(s[jt][3]);                             \
                uint2 pk;                                                                \
                pk.x = pk_bf16_rn(p0, p1);                                               \
                pk.y = pk_bf16_rn(p2, p3);                                               \
                *(uint2*)&plds[wid][qg][l15][jt * 16 + g * 4] = pk;                      \
            }                                                                            \
            bf16x8 pA0 = *(const bf16x8*)&plds[wid][qg][l15][g * 8];                     \
            bf16x8 pA1 = *(const bf16x8*)&plds[wid][qg][l15][32 + g * 8];                \
            lacc[qg] = __builtin_amdgcn_mfma_f32_16x16x32_bf16(pA0, ones, lacc[qg], 0, 0, 0); \
            lacc[qg] = __builtin_amdgcn_mfma_f32_16x16x32_bf16(pA1, ones, lacc[qg], 0, 0, 0); \
            _Pragma("unroll")                                                            \
            for (int jt = 0; jt < 4; jt++) {                                             \
                oacc[qg][jt] = __builtin_amdgcn_mfma_f32_16x16x32_bf16(pA0, vf[jt][0], oacc[qg][jt], 0, 0, 0); \
                oacc[qg][jt] = __builtin_amdgcn_mfma_f32_16x16x32_bf16(pA1, vf[jt][1], oacc[qg][jt], 0, 0, 0); \
            }                                                                            \
        }                                                                                \
        __syncthreads();                                                                 \
    }

    STAGE(0, 0)
    __syncthreads();

    for (int kt = 0; kt < TSEQ / 64; kt += 2) {
        BODY(0, 1, kt, 1)
        BODY(1, 0, kt + 1, (kt + 2 < TSEQ / 64))
    }
    #undef BODY
    #undef STAGE

    // oacc/lacc C-layout: row = q_local = g*4+r, col = l15. lacc columns are all
    // identical (B=ones), so the denominator for row r is lacc[qg][r] in-lane.
    #pragma unroll
    for (int qg = 0; qg < 2; qg++)
        #pragma unroll
        for (int r = 0; r < 4; r++) {
            float inv = 1.f / lacc[qg][r];
            long row = qrow + qg * 16 + g * 4 + r;
            #pragma unroll
            for (int jt = 0; jt < 4; jt++)
                ob[row * 1024 + h * 64 + jt * 16 + l15] = f2bf(oacc[qg][jt][r] * inv);
        }
}

// ---------------------------------------------------------------- launcher
extern "C" void kernel_launch(void* const* d_in, const int* in_sizes, int n_in,
                              void* d_out, int out_size, void* d_ws, size_t ws_size,
                              hipStream_t stream)
{
    const float* x    = (const float*)d_in[0];
    const float* Wqkv = (const float*)d_in[1];
    const float* bqkv = (const float*)d_in[2];
    const float* Wout = (const float*)d_in[3];
    const float* bout = (const float*)d_in[4];
    float* out = (float*)d_out;

    char* ws = (char*)d_ws;
    const size_t SZ_TOKD = (size_t)NTOK * 1024 * sizeof(short);   // 8 MB
    short* xb    = (short*)ws;                 ws += SZ_TOKD;
    short* wqkvt = (short*)ws;                 ws += (size_t)3072 * 1024 * sizeof(short);
    short* woutt = (short*)ws;                 ws += (size_t)1024 * 1024 * sizeof(short);
    short* qb    = (short*)ws;                 ws += SZ_TOKD;
    short* kb    = (short*)ws;                 ws += SZ_TOKD;
    short* vt    = (short*)ws;                 ws += SZ_TOKD;
    short* ob    = (short*)ws;                 ws += SZ_TOKD;
    if ((size_t)(ws - (char*)d_ws) > ws_size) return;   // workspace too small

    prep_kernel<<<8192, 256, 0, stream>>>(x, Wqkv, Wout, xb, wqkvt, woutt);

    gemm_bf16_kernel<0><<<dim3(NTOK / 128, 3072 / 128), 256, 0, stream>>>(
        xb, wqkvt, bqkv, qb, kb, vt, nullptr);

    flash_attn_kernel<<<dim3(TSEQ / 128, BATCH * HEADS), 256, 0, stream>>>(qb, kb, vt, ob);

    gemm_bf16_kernel<1><<<dim3(NTOK / 128, 1024 / 128), 256, 0, stream>>>(
        ob, woutt, bout, nullptr, nullptr, nullptr, out);
}